// Round 7
// baseline (88.020 us; speedup 1.0000x reference)
//
#include <hip/hip_runtime.h>
#include <float.h>

// NearestCluster: per-batch NN argmin via uniform 8^3 grid (exact).
// coords1 [L1=4096, N=8, C=3] f32 (reference), coords2 [L2=4096, N=8, C=3] f32 (query)
// out int32: [L2*N] argmin idx over L1 per batch, then [L2*N] batch idx.
//
// Numerics: bit-exact vs numpy f32 reference:
//   qq = (q0*q0 + q1*q1) + q2*q2         rr likewise (round each op, no fma)
//   dot = ((q0*r0) + (q1*r1)) + (q2*r2)
//   d2 = (qq + rr) - 2*dot  ==  fma(-2, dot, qq+rr)   (2*dot exact)
// Ties -> lowest ORIGINAL index (np.argmin first occurrence): every candidate
// carries its original index; all merges are lexicographic on (d2, idx).
//
// R7 post-mortem: ring kernel ~33us vs ~0.9us of actual distance VALU work --
// 8-lane groups diverged within the wave (union of 8 groups' control flow) and
// serialized on per-cell dependent loads. R8: ONE WAVE PER QUERY (uniform
// control flow), flat 3x3 range walk (x-cells contiguous -> 9 ranges, fixed
// 3x3 unrolled loop, all cs loads hoisted), points packed (x,y,z,idx) 16B with
// exact rr recompute. 32768 waves -> 32 waves/CU.
//
// Pruning exactness: any point outside the 3^3 cell neighborhood has an axis
// coordinate gap > 1/8 exactly (cell edges k/8 exact in f32; rx*8, qx*8 exact)
// => true d2 > lb = 0.015625 (exact). Computed-vs-true d2 error <= ~3.6e-6 for
// coords in [0,1]. Skip the full-scan fallback only when lb > bd + 4e-6 =>
// every pruned point's COMPUTED d2 > bd => cannot be the argmin nor a tie.
// Fallback (prob ~e^-33, wave-uniform branch) rescans all 4096 points with the
// same update rule (idempotent) -> exact in all cases.
//
// ws layout (540928 B; harness ws is ~268 MB):
//   int    cellStart[8][520]  (513 used: 512 cell starts + total)  16640 B
//   float4 pts[8][4096]       (x,y,z, idx-as-float) cell-ordered  524288 B
// Fallback to the verified R5 LDS brute-force kernel if ws too small.

constexpr int kL1 = 4096, kL2 = 4096, kN = 8;
constexpr int kCS = 520;                       // ints per batch in cellStart
constexpr size_t kOffPts = 8ull * kCS * 4;                   // 16640
constexpr size_t kWsBytes = kOffPts + 8ull * kL1 * 16;       // 540928

__device__ __forceinline__ float rr_exact(float x, float y, float z) {
  return __fadd_rn(__fadd_rn(__fmul_rn(x, x), __fmul_rn(y, y)), __fmul_rn(z, z));
}

// ---------------- Kernel 1: bin refs into 8^3 cells per batch ----------------
__global__ __launch_bounds__(1024)
void bin_kernel(const float* __restrict__ c1, int* __restrict__ cellStart,
                float4* __restrict__ pts) {
#pragma clang fp contract(off)
  __shared__ int cnt[512];
  const int tid = threadIdx.x;
  const int n = blockIdx.x;
  if (tid < 512) cnt[tid] = 0;
  __syncthreads();

  float xs[4], ys[4], zs[4];
  int cl[4];
#pragma unroll
  for (int k = 0; k < 4; ++k) {
    const int j = k * 1024 + tid;
    const float* p = c1 + (j * kN + n) * 3;
    const float x = p[0], y = p[1], z = p[2];
    xs[k] = x; ys[k] = y; zs[k] = z;
    const int cx = min(7, max(0, (int)(x * 8.0f)));
    const int cy = min(7, max(0, (int)(y * 8.0f)));
    const int cz = min(7, max(0, (int)(z * 8.0f)));
    cl[k] = (cz * 8 + cy) * 8 + cx;
    atomicAdd(&cnt[cl[k]], 1);
  }
  __syncthreads();

  // Exclusive prefix over 512 counts: wave 0, 8 cells/lane + shfl scan.
  if (tid < 64) {
    int loc[8], part = 0;
#pragma unroll
    for (int i = 0; i < 8; ++i) { loc[i] = cnt[tid * 8 + i]; part += loc[i]; }
    int inc = part;
#pragma unroll
    for (int off = 1; off < 64; off <<= 1) {
      const int v = __shfl_up(inc, off);
      if (tid >= off) inc += v;
    }
    int base = inc - part;
#pragma unroll
    for (int i = 0; i < 8; ++i) {
      const int c = tid * 8 + i;
      cellStart[n * kCS + c] = base;
      cnt[c] = base;                 // becomes scatter cursor
      base += loc[i];
    }
    if (tid == 0) cellStart[n * kCS + 512] = kL1;
  }
  __syncthreads();

#pragma unroll
  for (int k = 0; k < 4; ++k) {
    const int j = k * 1024 + tid;
    const int pos = atomicAdd(&cnt[cl[k]], 1);
    pts[n * kL1 + pos] =
        make_float4(xs[k], ys[k], zs[k], __int_as_float(j));
  }
}

// ---------------- Kernel 2: one wave per query, flat 3x3x3 walk ----------------
__global__ __launch_bounds__(256, 8)
void grid_nn_kernel(const int* __restrict__ cellStart, const float4* __restrict__ pts,
                    const float* __restrict__ c2, int* __restrict__ out) {
#pragma clang fp contract(off)
  const int n = blockIdx.y;                    // batch (uniform, SGPR)
  const int wave = threadIdx.x >> 6;
  const int lane = threadIdx.x & 63;
  const int qj = blockIdx.x * 4 + wave;        // query index within batch

  const float* p = c2 + (qj * kN + n) * 3;     // all lanes same addr: broadcast
  const float qx = p[0], qy = p[1], qz = p[2];
  const float qq = rr_exact(qx, qy, qz);
  const int cx = min(7, max(0, (int)(qx * 8.0f)));
  const int cy = min(7, max(0, (int)(qy * 8.0f)));
  const int cz = min(7, max(0, (int)(qz * 8.0f)));
  const int xlo = max(0, cx - 1), xhi = min(7, cx + 1);

  const int* __restrict__ cs = cellStart + n * kCS;
  const float4* __restrict__ P = pts + n * kL1;

  float bd = FLT_MAX;
  int bi = 0x7FFFFFFF;

  // Fixed 3x3 (z,y) loop -> fully unrolled; skips are wave-uniform branches.
#pragma unroll
  for (int dz = -1; dz <= 1; ++dz) {
#pragma unroll
    for (int dy = -1; dy <= 1; ++dy) {
      const int z = cz + dz, y = cy + dy;
      if (z < 0 || z > 7 || y < 0 || y > 7) continue;
      const int row = (z * 8 + y) * 8;
      const int s = cs[row + xlo];             // uniform-value loads
      const int e = cs[row + xhi + 1];
      for (int pp = s + lane; pp < e; pp += 64) {
        const float4 rp = P[pp];
        const int id = __float_as_int(rp.w);
        const float rr = rr_exact(rp.x, rp.y, rp.z);
        const float dot = __fadd_rn(
            __fadd_rn(__fmul_rn(qx, rp.x), __fmul_rn(qy, rp.y)),
            __fmul_rn(qz, rp.z));
        const float d2 = __fmaf_rn(-2.0f, dot, __fadd_rn(qq, rr));
        if (d2 < bd || (d2 == bd && id < bi)) { bd = d2; bi = id; }
      }
    }
  }

  // Merge across the wave (lexicographic on (d2, idx)).
#pragma unroll
  for (int m = 1; m <= 32; m <<= 1) {
    const float od = __shfl_xor(bd, m);
    const int oi = __shfl_xor(bi, m);
    if (od < bd || (od == bd && oi < bi)) { bd = od; bi = oi; }
  }

  // Fallback (wave-uniform, astronomically rare): rescan all points exactly.
  if (!(0.015625f > __fadd_rn(bd, 4e-6f))) {
    for (int pp = lane; pp < kL1; pp += 64) {
      const float4 rp = P[pp];
      const int id = __float_as_int(rp.w);
      const float rr = rr_exact(rp.x, rp.y, rp.z);
      const float dot = __fadd_rn(
          __fadd_rn(__fmul_rn(qx, rp.x), __fmul_rn(qy, rp.y)),
          __fmul_rn(qz, rp.z));
      const float d2 = __fmaf_rn(-2.0f, dot, __fadd_rn(qq, rr));
      if (d2 < bd || (d2 == bd && id < bi)) { bd = d2; bi = id; }
    }
#pragma unroll
    for (int m = 1; m <= 32; m <<= 1) {
      const float od = __shfl_xor(bd, m);
      const int oi = __shfl_xor(bi, m);
      if (od < bd || (od == bd && oi < bi)) { bd = od; bi = oi; }
    }
  }

  if (lane == 0) {
    out[qj * kN + n] = bi;
    out[kL2 * kN + qj * kN + n] = n;
  }
}

// ---------------- Fallback (verified R5/R6 brute force, LDS) ----------------
constexpr int kQPerBlock = 16;
constexpr int kQ = 4;
constexpr int kChunk = 1024;

__global__ __launch_bounds__(256, 4)
void nearest_kernel_lds(const float* __restrict__ c1, const float* __restrict__ c2,
                        int* __restrict__ out) {
#pragma clang fp contract(off)
  __shared__ float sRx[kChunk], sRy[kChunk], sRz[kChunk], sRr[kChunk];
  const int tid = threadIdx.x;
  const int n = blockIdx.y;
  const int wave = tid >> 6;
  const int lane = tid & 63;
  const int q0 = blockIdx.x * kQPerBlock + wave * kQ;

  float qxs[kQ], qys[kQ], qzs[kQ], qqs[kQ];
#pragma unroll
  for (int i = 0; i < kQ; ++i) {
    const float* p = c2 + ((q0 + i) * kN + n) * 3;
    qxs[i] = p[0]; qys[i] = p[1]; qzs[i] = p[2];
    qqs[i] = rr_exact(qxs[i], qys[i], qzs[i]);
  }
  float bd[kQ]; int bt[kQ];
#pragma unroll
  for (int i = 0; i < kQ; ++i) { bd[i] = FLT_MAX; bt[i] = 0; }

  for (int chunk = 0; chunk < kL1 / kChunk; ++chunk) {
    __syncthreads();
    {
      const int jb = chunk * kChunk + tid * 4;
      float x[4], y[4], z[4], w4[4];
#pragma unroll
      for (int k = 0; k < 4; ++k) {
        const float* p = c1 + ((jb + k) * kN + n) * 3;
        x[k] = p[0]; y[k] = p[1]; z[k] = p[2];
        w4[k] = rr_exact(x[k], y[k], z[k]);
      }
      *reinterpret_cast<float4*>(&sRx[tid * 4]) = make_float4(x[0], x[1], x[2], x[3]);
      *reinterpret_cast<float4*>(&sRy[tid * 4]) = make_float4(y[0], y[1], y[2], y[3]);
      *reinterpret_cast<float4*>(&sRz[tid * 4]) = make_float4(z[0], z[1], z[2], z[3]);
      *reinterpret_cast<float4*>(&sRr[tid * 4]) = make_float4(w4[0], w4[1], w4[2], w4[3]);
    }
    __syncthreads();
#pragma unroll
    for (int t = 0; t < kChunk / 256; ++t) {
      const int tg = chunk * (kChunk / 256) + t;
      const int base = t * 256 + lane * 4;
      const float4 x4 = *reinterpret_cast<const float4*>(&sRx[base]);
      const float4 y4 = *reinterpret_cast<const float4*>(&sRy[base]);
      const float4 z4 = *reinterpret_cast<const float4*>(&sRz[base]);
      const float4 r4 = *reinterpret_cast<const float4*>(&sRr[base]);
      const float xs[4] = {x4.x, x4.y, x4.z, x4.w};
      const float ys[4] = {y4.x, y4.y, y4.z, y4.w};
      const float zs[4] = {z4.x, z4.y, z4.z, z4.w};
      const float rs[4] = {r4.x, r4.y, r4.z, r4.w};
#pragma unroll
      for (int i = 0; i < kQ; ++i) {
        float d[4];
#pragma unroll
        for (int k = 0; k < 4; ++k) {
          const float dot = __fadd_rn(
              __fadd_rn(__fmul_rn(qxs[i], xs[k]), __fmul_rn(qys[i], ys[k])),
              __fmul_rn(qzs[i], zs[k]));
          d[k] = __fmaf_rn(-2.0f, dot, __fadd_rn(qqs[i], rs[k]));
        }
        const float old = bd[i];
        float m = fminf(fminf(d[0], d[1]), old);
        m = fminf(fminf(d[2], d[3]), m);
        bd[i] = m;
        if (m < old) bt[i] = tg;
      }
    }
  }
  int sel[kQ];
#pragma unroll
  for (int i = 0; i < kQ; ++i) sel[i] = bt[i] * 64 + lane;
#pragma unroll
  for (int m = 1; m <= 32; m <<= 1) {
#pragma unroll
    for (int i = 0; i < kQ; ++i) {
      const float od = __shfl_xor(bd[i], m);
      const int os = __shfl_xor(sel[i], m);
      if (od < bd[i] || (od == bd[i] && os < sel[i])) { bd[i] = od; sel[i] = os; }
    }
  }
#pragma unroll
  for (int i = 0; i < kQ; ++i) {
    if (lane == i) {
      const int j0 = sel[i] * 4;
      float best = FLT_MAX; int kk = 0;
#pragma unroll
      for (int k = 0; k < 4; ++k) {
        const float* p = c1 + ((j0 + k) * kN + n) * 3;
        const float r0 = p[0], r1 = p[1], r2 = p[2];
        const float rr = rr_exact(r0, r1, r2);
        const float dot = __fadd_rn(
            __fadd_rn(__fmul_rn(qxs[i], r0), __fmul_rn(qys[i], r1)),
            __fmul_rn(qzs[i], r2));
        const float dc = __fmaf_rn(-2.0f, dot, __fadd_rn(qqs[i], rr));
        if (dc < best) { best = dc; kk = k; }
      }
      out[(q0 + i) * kN + n] = j0 + kk;
      out[kL2 * kN + (q0 + i) * kN + n] = n;
    }
  }
}

extern "C" void kernel_launch(void* const* d_in, const int* in_sizes, int n_in,
                              void* d_out, int out_size, void* d_ws, size_t ws_size,
                              hipStream_t stream) {
  const float* c1 = (const float*)d_in[0];
  const float* c2 = (const float*)d_in[1];
  int* out = (int*)d_out;
  if (d_ws != nullptr && ws_size >= kWsBytes) {
    int* cellStart = (int*)d_ws;
    float4* pts = (float4*)((char*)d_ws + kOffPts);
    bin_kernel<<<dim3(kN), dim3(1024), 0, stream>>>(c1, cellStart, pts);
    grid_nn_kernel<<<dim3(kL2 / 4, kN), dim3(256), 0, stream>>>(
        cellStart, pts, c2, out);
  } else {
    dim3 grid(kL2 / kQPerBlock, kN);
    nearest_kernel_lds<<<grid, dim3(256), 0, stream>>>(c1, c2, out);
  }
}

// Round 8
// 82.177 us; speedup vs baseline: 1.0711x; 1.0711x over previous
//
#include <hip/hip_runtime.h>
#include <float.h>
#include <limits.h>

// NearestCluster: per-batch NN argmin via uniform 8^3 grid (exact).
// coords1 [L1=4096, N=8, C=3] f32 (reference), coords2 [L2=4096, N=8, C=3] f32 (query)
// out int32: [L2*N] argmin idx over L1 per batch, then [L2*N] batch idx.
//
// Numerics: bit-exact vs numpy f32 reference:
//   qq = (q0*q0 + q1*q1) + q2*q2         rr likewise (round each op, no fma)
//   dot = ((q0*r0) + (q1*r1)) + (q2*r2)
//   d2 = (qq + rr) - 2*dot  ==  fma(-2, dot, qq+rr)   (2*dot exact)
// Ties -> lowest ORIGINAL index: candidates carry orig idx; every update and
// merge is lexicographic on (d2, idx).
//
// R8 post-mortem: one-wave-per-query was STILL ~35us. The 3x3 unrolled walk
// kept the 18 cellStart loads inside 9 exec-masked sections -> 9 sequential
// (cs-load -> P-load) latency chains (~5us crit path/wave), ~24/64 lanes busy.
// R9: branch-free. (1) all 18 cs loads unconditional (clamped row, len
// cndmask'd to 0 for invalid sections) -> ONE latency stage; (2) register
// prefix-sum of 9 lens -> total T (wave-uniform); lane decodes global slots
// base+lane+64u to (section,offset) via unrolled cndmask chain; 4 point loads
// issue independently -> ONE more latency stage, full lane utilization.
// All arrays indexed only in fully-unrolled loops (stay in registers).
//
// Pruning exactness: any point outside the 3^3 neighborhood has an axis gap
// > 1/8 exactly => true d2 > lb = 0.015625 (exact in f32). Computed-vs-true
// d2 error <= ~3.6e-6. Skip the full-scan fallback only when lb > bd + 4e-6
// => pruned points' COMPUTED d2 > bd => never the argmin nor a tie. T=0 or
// empty neighborhood leaves bd=FLT_MAX -> fallback rescans all 4096 exactly.
//
// ws layout (540928 B): int cellStart[8][520]; float4 pts[8][4096] (x,y,z,idx).
// Fallback to the verified R5 LDS brute-force kernel if ws too small.

constexpr int kL1 = 4096, kL2 = 4096, kN = 8;
constexpr int kCS = 520;                       // ints per batch in cellStart
constexpr size_t kOffPts = 8ull * kCS * 4;                   // 16640
constexpr size_t kWsBytes = kOffPts + 8ull * kL1 * 16;       // 540928

__device__ __forceinline__ float rr_exact(float x, float y, float z) {
  return __fadd_rn(__fadd_rn(__fmul_rn(x, x), __fmul_rn(y, y)), __fmul_rn(z, z));
}

// ---------------- Kernel 1: bin refs into 8^3 cells per batch (R7-proven) ----
__global__ __launch_bounds__(1024)
void bin_kernel(const float* __restrict__ c1, int* __restrict__ cellStart,
                float4* __restrict__ pts) {
#pragma clang fp contract(off)
  __shared__ int cnt[512];
  const int tid = threadIdx.x;
  const int n = blockIdx.x;
  if (tid < 512) cnt[tid] = 0;
  __syncthreads();

  float xs[4], ys[4], zs[4];
  int cl[4];
#pragma unroll
  for (int k = 0; k < 4; ++k) {
    const int j = k * 1024 + tid;
    const float* p = c1 + (j * kN + n) * 3;
    const float x = p[0], y = p[1], z = p[2];
    xs[k] = x; ys[k] = y; zs[k] = z;
    const int cx = min(7, max(0, (int)(x * 8.0f)));
    const int cy = min(7, max(0, (int)(y * 8.0f)));
    const int cz = min(7, max(0, (int)(z * 8.0f)));
    cl[k] = (cz * 8 + cy) * 8 + cx;
    atomicAdd(&cnt[cl[k]], 1);
  }
  __syncthreads();

  // Exclusive prefix over 512 counts: wave 0, 8 cells/lane + shfl scan.
  if (tid < 64) {
    int loc[8], part = 0;
#pragma unroll
    for (int i = 0; i < 8; ++i) { loc[i] = cnt[tid * 8 + i]; part += loc[i]; }
    int inc = part;
#pragma unroll
    for (int off = 1; off < 64; off <<= 1) {
      const int v = __shfl_up(inc, off);
      if (tid >= off) inc += v;
    }
    int base = inc - part;
#pragma unroll
    for (int i = 0; i < 8; ++i) {
      const int c = tid * 8 + i;
      cellStart[n * kCS + c] = base;
      cnt[c] = base;                 // becomes scatter cursor
      base += loc[i];
    }
    if (tid == 0) cellStart[n * kCS + 512] = kL1;
  }
  __syncthreads();

#pragma unroll
  for (int k = 0; k < 4; ++k) {
    const int j = k * 1024 + tid;
    const int pos = atomicAdd(&cnt[cl[k]], 1);
    pts[n * kL1 + pos] = make_float4(xs[k], ys[k], zs[k], __int_as_float(j));
  }
}

// ------- Kernel 2: one wave per query, branch-free compacted 3x3x3 walk -------
__global__ __launch_bounds__(256, 6)
void grid_nn_kernel(const int* __restrict__ cellStart, const float4* __restrict__ pts,
                    const float* __restrict__ c2, int* __restrict__ out) {
#pragma clang fp contract(off)
  const int n = blockIdx.y;                    // batch (uniform)
  const int wave = threadIdx.x >> 6;
  const int lane = threadIdx.x & 63;
  const int qj = blockIdx.x * 4 + wave;        // query index within batch

  const float* p = c2 + (qj * kN + n) * 3;     // same addr all lanes: broadcast
  const float qx = p[0], qy = p[1], qz = p[2];
  const float qq = rr_exact(qx, qy, qz);
  const int cx = min(7, max(0, (int)(qx * 8.0f)));
  const int cy = min(7, max(0, (int)(qy * 8.0f)));
  const int cz = min(7, max(0, (int)(qz * 8.0f)));
  const int xlo = max(0, cx - 1), xhi = min(7, cx + 1);

  const int* __restrict__ cs = cellStart + n * kCS;
  const float4* __restrict__ P = pts + n * kL1;

  // 9 (z,y) sections, branch-free: 18 independent cs loads all in flight.
  int S[9], Lk[9], pre[10];
#pragma unroll
  for (int k = 0; k < 9; ++k) {
    const int dz = k / 3 - 1, dy = k % 3 - 1;
    const int z = cz + dz, y = cy + dy;
    const bool valid = ((unsigned)z <= 7u) && ((unsigned)y <= 7u);
    const int zc = min(7, max(0, z)), yc = min(7, max(0, y));
    const int row = (zc * 8 + yc) * 8;
    const int s = cs[row + xlo];
    const int e = cs[row + xhi + 1];
    S[k] = s;
    Lk[k] = valid ? (e - s) : 0;
  }
  pre[0] = 0;
#pragma unroll
  for (int k = 0; k < 9; ++k) pre[k + 1] = pre[k] + Lk[k];
  const int T = pre[9];                        // wave-uniform total candidates

  float bd = FLT_MAX;
  int bi = INT_MAX;

  for (int base = 0; base < T; base += 256) {  // 1 trip typ. (T ~ 216)
    int g[4], a[4];
#pragma unroll
    for (int u = 0; u < 4; ++u) {
      g[u] = base + lane + u * 64;
      int ad = 0;                              // g>=T decodes to 0 (in-bounds)
#pragma unroll
      for (int k = 0; k < 9; ++k) {
        const bool in = (g[u] >= pre[k]) && (g[u] < pre[k + 1]);
        ad = in ? (S[k] + (g[u] - pre[k])) : ad;
      }
      a[u] = ad;
    }
    float4 rp[4];
#pragma unroll
    for (int u = 0; u < 4; ++u) rp[u] = P[a[u]];   // 4 independent loads
#pragma unroll
    for (int u = 0; u < 4; ++u) {
      const int id = __float_as_int(rp[u].w);
      const float rr = rr_exact(rp[u].x, rp[u].y, rp[u].z);
      const float dot = __fadd_rn(
          __fadd_rn(__fmul_rn(qx, rp[u].x), __fmul_rn(qy, rp[u].y)),
          __fmul_rn(qz, rp[u].z));
      const float d2 = __fmaf_rn(-2.0f, dot, __fadd_rn(qq, rr));
      if (g[u] < T && (d2 < bd || (d2 == bd && id < bi))) { bd = d2; bi = id; }
    }
  }

  // Merge across the wave (lexicographic on (d2, idx)).
#pragma unroll
  for (int m = 1; m <= 32; m <<= 1) {
    const float od = __shfl_xor(bd, m);
    const int oi = __shfl_xor(bi, m);
    if (od < bd || (od == bd && oi < bi)) { bd = od; bi = oi; }
  }

  // Fallback (wave-uniform, astronomically rare): rescan all points exactly.
  if (!(0.015625f > __fadd_rn(bd, 4e-6f))) {
    for (int pp = lane; pp < kL1; pp += 64) {
      const float4 rp = P[pp];
      const int id = __float_as_int(rp.w);
      const float rr = rr_exact(rp.x, rp.y, rp.z);
      const float dot = __fadd_rn(
          __fadd_rn(__fmul_rn(qx, rp.x), __fmul_rn(qy, rp.y)),
          __fmul_rn(qz, rp.z));
      const float d2 = __fmaf_rn(-2.0f, dot, __fadd_rn(qq, rr));
      if (d2 < bd || (d2 == bd && id < bi)) { bd = d2; bi = id; }
    }
#pragma unroll
    for (int m = 1; m <= 32; m <<= 1) {
      const float od = __shfl_xor(bd, m);
      const int oi = __shfl_xor(bi, m);
      if (od < bd || (od == bd && oi < bi)) { bd = od; bi = oi; }
    }
  }

  if (lane == 0) {
    out[qj * kN + n] = bi;
    out[kL2 * kN + qj * kN + n] = n;
  }
}

// ---------------- Fallback (verified R5/R6 brute force, LDS) ----------------
constexpr int kQPerBlock = 16;
constexpr int kQ = 4;
constexpr int kChunk = 1024;

__global__ __launch_bounds__(256, 4)
void nearest_kernel_lds(const float* __restrict__ c1, const float* __restrict__ c2,
                        int* __restrict__ out) {
#pragma clang fp contract(off)
  __shared__ float sRx[kChunk], sRy[kChunk], sRz[kChunk], sRr[kChunk];
  const int tid = threadIdx.x;
  const int n = blockIdx.y;
  const int wave = tid >> 6;
  const int lane = tid & 63;
  const int q0 = blockIdx.x * kQPerBlock + wave * kQ;

  float qxs[kQ], qys[kQ], qzs[kQ], qqs[kQ];
#pragma unroll
  for (int i = 0; i < kQ; ++i) {
    const float* p = c2 + ((q0 + i) * kN + n) * 3;
    qxs[i] = p[0]; qys[i] = p[1]; qzs[i] = p[2];
    qqs[i] = rr_exact(qxs[i], qys[i], qzs[i]);
  }
  float bd[kQ]; int bt[kQ];
#pragma unroll
  for (int i = 0; i < kQ; ++i) { bd[i] = FLT_MAX; bt[i] = 0; }

  for (int chunk = 0; chunk < kL1 / kChunk; ++chunk) {
    __syncthreads();
    {
      const int jb = chunk * kChunk + tid * 4;
      float x[4], y[4], z[4], w4[4];
#pragma unroll
      for (int k = 0; k < 4; ++k) {
        const float* p = c1 + ((jb + k) * kN + n) * 3;
        x[k] = p[0]; y[k] = p[1]; z[k] = p[2];
        w4[k] = rr_exact(x[k], y[k], z[k]);
      }
      *reinterpret_cast<float4*>(&sRx[tid * 4]) = make_float4(x[0], x[1], x[2], x[3]);
      *reinterpret_cast<float4*>(&sRy[tid * 4]) = make_float4(y[0], y[1], y[2], y[3]);
      *reinterpret_cast<float4*>(&sRz[tid * 4]) = make_float4(z[0], z[1], z[2], z[3]);
      *reinterpret_cast<float4*>(&sRr[tid * 4]) = make_float4(w4[0], w4[1], w4[2], w4[3]);
    }
    __syncthreads();
#pragma unroll
    for (int t = 0; t < kChunk / 256; ++t) {
      const int tg = chunk * (kChunk / 256) + t;
      const int base = t * 256 + lane * 4;
      const float4 x4 = *reinterpret_cast<const float4*>(&sRx[base]);
      const float4 y4 = *reinterpret_cast<const float4*>(&sRy[base]);
      const float4 z4 = *reinterpret_cast<const float4*>(&sRz[base]);
      const float4 r4 = *reinterpret_cast<const float4*>(&sRr[base]);
      const float xs[4] = {x4.x, x4.y, x4.z, x4.w};
      const float ys[4] = {y4.x, y4.y, y4.z, y4.w};
      const float zs[4] = {z4.x, z4.y, z4.z, z4.w};
      const float rs[4] = {r4.x, r4.y, r4.z, r4.w};
#pragma unroll
      for (int i = 0; i < kQ; ++i) {
        float d[4];
#pragma unroll
        for (int k = 0; k < 4; ++k) {
          const float dot = __fadd_rn(
              __fadd_rn(__fmul_rn(qxs[i], xs[k]), __fmul_rn(qys[i], ys[k])),
              __fmul_rn(qzs[i], zs[k]));
          d[k] = __fmaf_rn(-2.0f, dot, __fadd_rn(qqs[i], rs[k]));
        }
        const float old = bd[i];
        float m = fminf(fminf(d[0], d[1]), old);
        m = fminf(fminf(d[2], d[3]), m);
        bd[i] = m;
        if (m < old) bt[i] = tg;
      }
    }
  }
  int sel[kQ];
#pragma unroll
  for (int i = 0; i < kQ; ++i) sel[i] = bt[i] * 64 + lane;
#pragma unroll
  for (int m = 1; m <= 32; m <<= 1) {
#pragma unroll
    for (int i = 0; i < kQ; ++i) {
      const float od = __shfl_xor(bd[i], m);
      const int os = __shfl_xor(sel[i], m);
      if (od < bd[i] || (od == bd[i] && os < sel[i])) { bd[i] = od; sel[i] = os; }
    }
  }
#pragma unroll
  for (int i = 0; i < kQ; ++i) {
    if (lane == i) {
      const int j0 = sel[i] * 4;
      float best = FLT_MAX; int kk = 0;
#pragma unroll
      for (int k = 0; k < 4; ++k) {
        const float* p = c1 + ((j0 + k) * kN + n) * 3;
        const float r0 = p[0], r1 = p[1], r2 = p[2];
        const float rr = rr_exact(r0, r1, r2);
        const float dot = __fadd_rn(
            __fadd_rn(__fmul_rn(qxs[i], r0), __fmul_rn(qys[i], r1)),
            __fmul_rn(qzs[i], r2));
        const float dc = __fmaf_rn(-2.0f, dot, __fadd_rn(qqs[i], rr));
        if (dc < best) { best = dc; kk = k; }
      }
      out[(q0 + i) * kN + n] = j0 + kk;
      out[kL2 * kN + (q0 + i) * kN + n] = n;
    }
  }
}

extern "C" void kernel_launch(void* const* d_in, const int* in_sizes, int n_in,
                              void* d_out, int out_size, void* d_ws, size_t ws_size,
                              hipStream_t stream) {
  const float* c1 = (const float*)d_in[0];
  const float* c2 = (const float*)d_in[1];
  int* out = (int*)d_out;
  if (d_ws != nullptr && ws_size >= kWsBytes) {
    int* cellStart = (int*)d_ws;
    float4* pts = (float4*)((char*)d_ws + kOffPts);
    bin_kernel<<<dim3(kN), dim3(1024), 0, stream>>>(c1, cellStart, pts);
    grid_nn_kernel<<<dim3(kL2 / 4, kN), dim3(256), 0, stream>>>(
        cellStart, pts, c2, out);
  } else {
    dim3 grid(kL2 / kQPerBlock, kN);
    nearest_kernel_lds<<<grid, dim3(256), 0, stream>>>(c1, c2, out);
  }
}